// Round 12
// baseline (304.329 us; speedup 1.0000x reference)
//
#include <hip/hip_runtime.h>

#define DEVI __device__ __forceinline__

typedef _Float16 f16;
typedef _Float16 f16x8 __attribute__((ext_vector_type(8)));
typedef float f32x4 __attribute__((ext_vector_type(4)));
typedef unsigned int u32;
typedef unsigned long long u64;

#define MM 3
#define BBATCH 8192
#define DDIM 2000
#define ZDIM 256
#define KATT 40
#define K0P 2048
#define N0 1024
#define N1 512
#define N2 256

typedef __attribute__((address_space(1))) u32 gu32;
typedef __attribute__((address_space(3))) u32 lu32;

DEVI void async16(const void* g, void* l) {
  __builtin_amdgcn_global_load_lds((const gu32*)g, (lu32*)l, 16, 0, 0);
}

// ---------------- x -> fp16 (K padded 2000->2048) + small converts (aff, W) ----------------
__global__ void k_convx(const float* __restrict__ x, f16* __restrict__ xh,
                        const float* __restrict__ aff, const float* __restrict__ W,
                        f16* __restrict__ affH, f16* __restrict__ WH) {
  int idx0 = blockIdx.x * 256 + threadIdx.x;
  if (idx0 < 2 * 128 * 128) affH[idx0] = (f16)aff[idx0];
  if (idx0 < 3 * 64 * 128) {
    int m = idx0 >> 13;
    int k = (idx0 >> 7) & 63;
    int f = idx0 & 127;
    WH[idx0] = (k < KATT) ? (f16)W[(m * KATT + k) * 128 + f] : (f16)0.f;
  }
  const long long nch = (long long)MM * BBATCH * (K0P / 8);
  for (long long idx = (long long)blockIdx.x * blockDim.x + threadIdx.x; idx < nch;
       idx += (long long)gridDim.x * blockDim.x) {
    int c8 = (int)(idx & 255);
    long long row = idx >> 8;
    union { f16 h[8]; f16x8 v; } u;
    if (c8 < DDIM / 8) {
      const float* src = x + row * DDIM + c8 * 8;
      float4 a = *reinterpret_cast<const float4*>(src);
      float4 b = *reinterpret_cast<const float4*>(src + 4);
      u.h[0] = (f16)a.x; u.h[1] = (f16)a.y; u.h[2] = (f16)a.z; u.h[3] = (f16)a.w;
      u.h[4] = (f16)b.x; u.h[5] = (f16)b.y; u.h[6] = (f16)b.z; u.h[7] = (f16)b.w;
    } else {
      for (int j = 0; j < 8; ++j) u.h[j] = (f16)0.f;
    }
    *reinterpret_cast<f16x8*>(xh + row * K0P + c8 * 8) = u.v;
  }
}

// ---------------- weight transpose+convert: w[m][K][N] f32 -> wt[m][N][Kpad] f16 ----------------
__global__ void k_wt(const float* __restrict__ w, f16* __restrict__ wt, int K, int Kpad, int N) {
  __shared__ float tile[32][33];
  int m = blockIdx.z;
  int k0 = blockIdx.x * 32, n0 = blockIdx.y * 32;
  const float* wm = w + (long long)m * K * N;
  f16* wtm = wt + (long long)m * N * Kpad;
  for (int p = 0; p < 4; ++p) {
    int idx = threadIdx.x + p * 256;
    int kk = idx >> 5, nn = idx & 31;
    float v = 0.f;
    if (k0 + kk < K) v = wm[(long long)(k0 + kk) * N + n0 + nn];
    tile[kk][nn] = v;
  }
  __syncthreads();
  for (int p = 0; p < 4; ++p) {
    int idx = threadIdx.x + p * 256;
    int nn = idx >> 5, kk = idx & 31;
    wtm[(long long)(n0 + nn) * Kpad + k0 + kk] = (f16)tile[kk][nn];
  }
}

// ---------------- GEMM (f16 inputs): C[m] = relu(A[m] @ BT[m]^T + bias), 128x128, BK=64 ----------------
template <int OUTF16>
__global__ __launch_bounds__(256, 2) void k_gemm(const f16* __restrict__ A,
                                                 const f16* __restrict__ BT,
                                                 const float* __restrict__ bias,
                                                 f16* __restrict__ outh,
                                                 float* __restrict__ outf,
                                                 f16* __restrict__ tH, int K, int N) {
  __shared__ f16 As[128 * 64];
  __shared__ f16 Bs[128 * 64];
  const int m = blockIdx.z;
  const int gm0 = blockIdx.y * 128;
  const int gn0 = blockIdx.x * 128;
  const int tid = threadIdx.x;
  const int wave = tid >> 6, lane = tid & 63;
  const int wr = wave >> 1, wc = wave & 1;

  const f16* Am = A + (long long)m * BBATCH * K;
  const f16* Bm = BT + (long long)m * N * K;

  const int srow = wave * 32 + (lane >> 3);
  const int sslot = (lane & 7) ^ (lane >> 3);
  const f16* aSrc = Am + (long long)(gm0 + srow) * K + sslot * 8;
  const f16* bSrc = Bm + (long long)(gn0 + srow) * K + sslot * 8;
  char* AsB = (char*)As;
  char* BsB = (char*)Bs;

  f32x4 zero = {0.f, 0.f, 0.f, 0.f};
  f32x4 acc[4][4];
  for (int i = 0; i < 4; ++i)
    for (int j = 0; j < 4; ++j) acc[i][j] = zero;

  for (int kt = 0; kt < K; kt += 64) {
    if (kt) __syncthreads();
#pragma unroll
    for (int q = 0; q < 4; ++q) {
      async16(aSrc + (long long)q * 8 * K + kt, AsB + (wave * 32 + q * 8) * 128);
      async16(bSrc + (long long)q * 8 * K + kt, BsB + (wave * 32 + q * 8) * 128);
    }
    __syncthreads();
#pragma unroll
    for (int ks = 0; ks < 2; ++ks) {
      f16x8 af[4], bf[4];
#pragma unroll
      for (int i = 0; i < 4; ++i) {
        int row = wr * 64 + i * 16 + (lane & 15);
        int slot = (ks * 4 + (lane >> 4)) ^ (row & 7);
        af[i] = *reinterpret_cast<const f16x8*>(AsB + row * 128 + slot * 16);
      }
#pragma unroll
      for (int j = 0; j < 4; ++j) {
        int row = wc * 64 + j * 16 + (lane & 15);
        int slot = (ks * 4 + (lane >> 4)) ^ (row & 7);
        bf[j] = *reinterpret_cast<const f16x8*>(BsB + row * 128 + slot * 16);
      }
#pragma unroll
      for (int i = 0; i < 4; ++i)
#pragma unroll
        for (int j = 0; j < 4; ++j)
          acc[i][j] = __builtin_amdgcn_mfma_f32_16x16x32_f16(af[i], bf[j], acc[i][j], 0, 0, 0);
    }
  }

  const int rowl = (lane >> 4) * 4;
  const int coll = lane & 15;
  for (int j = 0; j < 4; ++j) {
    int col = gn0 + wc * 64 + j * 16 + coll;
    float bv = bias[m * N + col];
    for (int i = 0; i < 4; ++i) {
      int row0 = gm0 + wr * 64 + i * 16 + rowl;
      for (int r = 0; r < 4; ++r) {
        float v = acc[i][j][r] + bv;
        v = v > 0.f ? v : 0.f;
        if constexpr (OUTF16) {
          outh[((long long)m * BBATCH + row0 + r) * N + col] = (f16)v;
        } else {
          outf[((long long)m * BBATCH + row0 + r) * N + col] = v;
          tH[((long long)(m * BBATCH + row0 + r) * 2 + (col & 1)) * 128 + (col >> 1)] = (f16)v;
        }
      }
    }
  }
}

// ---------------- minimal-barrier tri-buffered GEMM: BM=256 BN=128 BK=64 ----------------
// 512 thr = 8 waves (4M x 2N), per-wave 64x64 (acc[4][4], 32 MFMA/tile). LDS = 3 x 48KB
// (buf t%3: A[256][64] @+0, B[128][64] @+32768; rows 128B, XOR slot swizzle, staged linear
// with pre-swizzled global source). ONE barrier per K-tile; all ds_reads / MFMA are plain
// HIP, compiler-scheduled (fine-grained lgkmcnt). Ledger: stage(u+2) issued inside tile u
// (6 loads/thread). Entering tile u: in-flight = tile u's 6 + tile u+1's 6 -> vmcnt(6)
// retires tile u exactly (issued one full tile earlier -> no stall); entering NT-1 nothing
// is in flight -> vmcnt(0) free. WAR: tile u-1's ds_reads are register-complete before each
// wave's boundary-barrier arrival (compiler lgkm waits precede the consuming MFMAs), and
// stage(u+2) (which overwrites buf[(u-1)%3]) is issued only after that barrier.
template <int OUTF16>
__global__ __launch_bounds__(512, 1) void k_gemmt3(const f16* __restrict__ A,
                                                   const f16* __restrict__ BT,
                                                   const float* __restrict__ bias,
                                                   f16* __restrict__ outh, int K, int N) {
  extern __shared__ char lds[];  // 3 * 49152 = 147456
  // XCD-aware bijective swizzle (nwg multiple of 8: 768 / 384).
  const int lin = blockIdx.y * gridDim.x + blockIdx.x;
  const int cpx = (gridDim.x * gridDim.y) >> 3;
  const int swz = (lin & 7) * cpx + (lin >> 3);
  const int bx = swz % gridDim.x;
  const int byy = swz / gridDim.x;  // 0..95
  const int m = byy >> 5;
  const int gm0 = (byy & 31) * 256;
  const int gn0 = bx * 128;

  const int tid = threadIdx.x;
  const int wave = tid >> 6, lane = tid & 63;
  const int wR = wave >> 1;  // 0..3 : 64-row band
  const int wC = wave & 1;   // 0..1 : 64-col band
  const int lrow = lane & 15;
  const int l4 = lane >> 4;

  const f16* Am = A + (long long)m * BBATCH * K;
  const f16* Bm = BT + (long long)m * N * K;
  const int srow = tid >> 3;                // 0..63
  const int slog = (tid & 7) ^ (srow & 7);  // pre-swizzled logical slot for phys slot tid&7

  auto stage = [&](int t) {  // 6 loads: A rows srow+{0,64,128,192}, B rows srow+{0,64}
    char* buf = lds + (t % 3) * 49152;
    const long long kt = (long long)t << 6;
    const f16* sa = Am + (long long)(gm0 + srow) * K + kt + slog * 8;
    char* da = buf + srow * 128 + (tid & 7) * 16;
#pragma unroll
    for (int j = 0; j < 4; ++j) async16(sa + (long long)j * 64 * K, da + j * 8192);
    const f16* sb = Bm + (long long)(gn0 + srow) * K + kt + slog * 8;
    char* db = buf + 32768 + srow * 128 + (tid & 7) * 16;
    async16(sb, db);
    async16(sb + (long long)64 * K, db + 8192);
  };

  f16x8 af[2][4], bf[2][4];
  f32x4 acc[4][4];
  f32x4 zero = {0.f, 0.f, 0.f, 0.f};
#pragma unroll
  for (int i = 0; i < 4; ++i)
#pragma unroll
    for (int j = 0; j < 4; ++j) acc[i][j] = zero;

  const int NT = K >> 6;  // 32 (L0) / 16 (L1)
  stage(0);
  stage(1);

  for (int u = 0; u < NT; ++u) {
    if (u < NT - 1) {
      asm volatile("s_waitcnt vmcnt(6)" ::: "memory");
    } else {
      asm volatile("s_waitcnt vmcnt(0)" ::: "memory");
    }
    __builtin_amdgcn_s_barrier();
    __builtin_amdgcn_sched_barrier(0);
    const char* bufA = lds + (u % 3) * 49152;
    const char* bufB = bufA + 32768;
    if (u + 2 < NT) stage(u + 2);
#pragma unroll
    for (int ks = 0; ks < 2; ++ks) {
#pragma unroll
      for (int mf = 0; mf < 4; ++mf) {
        int row = wR * 64 + mf * 16 + lrow;
        int slot = ((ks * 4 + l4) ^ (row & 7)) * 16;
        af[ks][mf] = *reinterpret_cast<const f16x8*>(bufA + row * 128 + slot);
      }
#pragma unroll
      for (int nf = 0; nf < 4; ++nf) {
        int row = wC * 64 + nf * 16 + lrow;
        int slot = ((ks * 4 + l4) ^ (row & 7)) * 16;
        bf[ks][nf] = *reinterpret_cast<const f16x8*>(bufB + row * 128 + slot);
      }
    }
    __builtin_amdgcn_s_setprio(1);
#pragma unroll
    for (int ks = 0; ks < 2; ++ks)
#pragma unroll
      for (int mf = 0; mf < 4; ++mf)
#pragma unroll
        for (int nf = 0; nf < 4; ++nf)
          acc[mf][nf] = __builtin_amdgcn_mfma_f32_16x16x32_f16(af[ks][mf], bf[ks][nf], acc[mf][nf], 0, 0, 0);
    __builtin_amdgcn_s_setprio(0);
  }

  const int rowl = (lane >> 4) * 4;
  const int coll = lane & 15;
#pragma unroll
  for (int nf = 0; nf < 4; ++nf) {
    int col = gn0 + wC * 64 + nf * 16 + coll;
    float bv = bias[m * N + col];
#pragma unroll
    for (int mf = 0; mf < 4; ++mf) {
      int row0 = gm0 + wR * 64 + mf * 16 + rowl;
#pragma unroll
      for (int r = 0; r < 4; ++r) {
        float v = acc[mf][nf][r] + bv;
        v = v > 0.f ? v : 0.f;
        outh[((long long)m * BBATCH + row0 + r) * N + col] = (f16)v;
      }
    }
  }
}

// ---------------- small GEMMs for the attention tail ----------------
__global__ __launch_bounds__(256, 2) void k_sg(const f16* __restrict__ tH,
                                               const f16* __restrict__ affH,
                                               const f16* __restrict__ WH,
                                               f16* __restrict__ u, float* __restrict__ WtG) {
  __shared__ f16 As[128 * 128];
  __shared__ f16 Bs[128 * 128];
  const int zb = blockIdx.z;
  const int gm0 = blockIdx.y * 128;
  const bool isU = (zb < 3);
  const int p = isU ? zb : zb - 3;
  const int src = isU ? ((p == 0) ? 1 : 2) : p;
  const f16* Am = tH + (long long)src * 16384 * 128;
  const f16* Bm;
  int brows;
  if (isU) {
    int km = (p == 1) ? 1 : 0;
    Bm = affH + km * 128 * 128;
    brows = 128;
  } else {
    Bm = WH + p * 64 * 128;
    brows = 64;
  }

  const int tid = threadIdx.x;
  const int wave = tid >> 6, lane = tid & 63;
  const int wr = wave >> 1, wc = wave & 1;
  char* AsB = (char*)As;
  char* BsB = (char*)Bs;

#pragma unroll
  for (int q = 0; q < 8; ++q) {
    int sb = q * 4 + wave;
    int row = sb * 4 + (lane >> 4);
    int lsl = (lane & 15) ^ (row & 7);
    async16(Am + (long long)(gm0 + row) * 128 + lsl * 8, AsB + sb * 1024);
    if (sb * 4 < brows)
      async16(Bm + (long long)row * 128 + lsl * 8, BsB + sb * 1024);
  }
  if (brows == 64) {
    f16x8 z8 = {};
    for (int idx = tid; idx < 1024; idx += 256) {
      int row = 64 + (idx >> 4), sl = idx & 15;
      *reinterpret_cast<f16x8*>(BsB + row * 256 + sl * 16) = z8;
    }
  }
  __syncthreads();

  f32x4 zero = {0.f, 0.f, 0.f, 0.f};
  f32x4 acc[4][4];
  for (int i = 0; i < 4; ++i)
    for (int j = 0; j < 4; ++j) acc[i][j] = zero;

#pragma unroll
  for (int ks = 0; ks < 4; ++ks) {
    f16x8 af[4], bf[4];
#pragma unroll
    for (int i = 0; i < 4; ++i) {
      int row = wr * 64 + i * 16 + (lane & 15);
      int slot = (ks * 4 + (lane >> 4)) ^ (row & 7);
      af[i] = *reinterpret_cast<const f16x8*>(AsB + row * 256 + slot * 16);
    }
#pragma unroll
    for (int j = 0; j < 4; ++j) {
      int row = wc * 64 + j * 16 + (lane & 15);
      int slot = (ks * 4 + (lane >> 4)) ^ (row & 7);
      bf[j] = *reinterpret_cast<const f16x8*>(BsB + row * 256 + slot * 16);
    }
#pragma unroll
    for (int i = 0; i < 4; ++i)
#pragma unroll
      for (int j = 0; j < 4; ++j)
        acc[i][j] = __builtin_amdgcn_mfma_f32_16x16x32_f16(af[i], bf[j], acc[i][j], 0, 0, 0);
  }

  const int rowl = (lane >> 4) * 4;
  const int coll = lane & 15;
  if (isU) {
    for (int j = 0; j < 4; ++j) {
      int col = wc * 64 + j * 16 + coll;
      for (int i = 0; i < 4; ++i) {
        int row0 = gm0 + wr * 64 + i * 16 + rowl;
        for (int r = 0; r < 4; ++r)
          u[((long long)p * 16384 + row0 + r) * 128 + col] = (f16)acc[i][j][r];
      }
    }
  } else if (wc == 0) {
    for (int j = 0; j < 4; ++j) {
      int col = j * 16 + coll;
      for (int i = 0; i < 4; ++i) {
        int row0 = gm0 + wr * 64 + i * 16 + rowl;
        for (int r = 0; r < 4; ++r)
          WtG[((long long)p * 16384 + row0 + r) * 64 + col] = acc[i][j][r];
      }
    }
  }
}

// ---------------- fused tail: afm dots + tanh/softmax + coalesced output ----------------
DEVI float dot128(const f16* __restrict__ a, const f16* __restrict__ b) {
  float s = 0.f;
#pragma unroll
  for (int ch = 0; ch < 16; ++ch) {
    f16x8 av = *reinterpret_cast<const f16x8*>(a + ch * 8);
    f16x8 bv = *reinterpret_cast<const f16x8*>(b + ch * 8);
#pragma unroll
    for (int q = 0; q < 8; ++q) s += (float)av[q] * (float)bv[q];
  }
  return s;
}

DEVI float ftanh(float x) {
  x = fminf(fmaxf(x, -15.f), 15.f);
  float t = __expf(-2.f * x);
  return (1.f - t) / (1.f + t);
}

#define BB 32
__global__ void k_tail(const float* __restrict__ z, const f16* __restrict__ tH,
                       const f16* __restrict__ u, const float* __restrict__ WtG,
                       const float* __restrict__ Wh, float* __restrict__ out) {
  __shared__ float aa[BB][6][2];
  const int tid = threadIdx.x;
  const int bbase = blockIdx.x * BB;

  if (tid < BB * 6) {
    int bb = tid / 6, q = tid % 6;
    int b = bbase + bb;
    int i = q >> 1;
    int j = (q & 1) ? ((i == 2) ? 1 : 2) : ((i == 0) ? 1 : 0);
    int a = i < j ? i : j;
    int b2 = i < j ? j : i;
    int pidx = a + b2 - 1;
    bool trans = (i > j);

    float afm[2][2];
#pragma unroll
    for (int c = 0; c < 2; ++c)
#pragma unroll
      for (int d = 0; d < 2; ++d)
        afm[c][d] = dot128(tH + ((long long)(a * BBATCH + b) * 2 + c) * 128,
                           u + ((long long)pidx * 16384 + b * 2 + d) * 128);

    float m00, m01, m10, m11;
    if (!trans) { m00 = afm[0][0]; m01 = afm[0][1]; m10 = afm[1][0]; m11 = afm[1][1]; }
    else        { m00 = afm[0][0]; m01 = afm[1][0]; m10 = afm[0][1]; m11 = afm[1][1]; }

    const float* wb0 = WtG + ((long long)b2 * 16384 + b * 2 + 0) * 64;
    const float* wb1 = WtG + ((long long)b2 * 16384 + b * 2 + 1) * 64;
    const float* wa0 = WtG + ((long long)a * 16384 + b * 2 + 0) * 64;
    const float* wa1 = WtG + ((long long)a * 16384 + b * 2 + 1) * 64;
    const float* wh = Wh + (i * 3 + j) * KATT;
    float s0 = 0.f, s1 = 0.f;
    for (int k = 0; k < KATT; ++k) {
      float a0v = wa0[k], a1v = wa1[k];
      float h0 = ftanh(wb0[k] + a0v * m00 + a1v * m10);
      float h1 = ftanh(wb1[k] + a0v * m01 + a1v * m11);
      float w = wh[k];
      s0 += w * h0;
      s1 += w * h1;
    }
    float mx = fmaxf(s0, s1);
    float e0 = __expf(s0 - mx), e1 = __expf(s1 - mx);
    float inv = 1.f / (e0 + e1);
    aa[bb][q][0] = e0 * inv;
    aa[bb][q][1] = e1 * inv;
  }
  __syncthreads();

  for (int idx = tid; idx < BB * 6 * 256; idx += 256) {
    int zz = idx & 255;
    int r = idx >> 8;
    int q = r % 6;
    int bb = r / 6;
    int iM = q >> 1;
    float av = aa[bb][q][zz & 1];
    float tv = z[((long long)iM * BBATCH + bbase + bb) * ZDIM + zz];
    out[(long long)(bbase + bb) * 1536 + q * 256 + zz] = av * tv;
  }
}

extern "C" void kernel_launch(void* const* d_in, const int* in_sizes, int n_in, void* d_out,
                              int out_size, void* d_ws, size_t ws_size, hipStream_t stream) {
  const float* x = (const float*)d_in[0];
  const float* w0 = (const float*)d_in[1];
  const float* b0 = (const float*)d_in[2];
  const float* w1 = (const float*)d_in[3];
  const float* b1 = (const float*)d_in[4];
  const float* w2 = (const float*)d_in[5];
  const float* b2 = (const float*)d_in[6];
  const float* aff = (const float*)d_in[7];
  const float* W = (const float*)d_in[8];
  const float* Wh = (const float*)d_in[9];
  float* zout = (float*)d_out;
  float* cout = zout + (long long)MM * BBATCH * ZDIM;

  char* ws = (char*)d_ws;
  size_t off = 0;
  auto alloc = [&](size_t bytes) {
    char* p = ws + off;
    off += (bytes + 255) & ~(size_t)255;
    return p;
  };
  f16* xh = (f16*)alloc((size_t)MM * BBATCH * K0P * 2);
  f16* wT0 = (f16*)alloc((size_t)MM * N0 * K0P * 2);
  f16* wT1 = (f16*)alloc((size_t)MM * N1 * N0 * 2);
  f16* wT2 = (f16*)alloc((size_t)MM * N2 * N1 * 2);
  f16* h0 = (f16*)alloc((size_t)MM * BBATCH * N0 * 2);
  f16* h1 = (f16*)alloc((size_t)MM * BBATCH * N1 * 2);
  f16* affH = (f16*)alloc((size_t)2 * 128 * 128 * 2);
  f16* WH = (f16*)alloc((size_t)3 * 64 * 128 * 2);
  if (ws_size < off) return;

  // tail buffers alias xh (dead after L0 GEMM)
  f16* tH = (f16*)xh;
  f16* u = (f16*)((char*)xh + (size_t)3 * 16384 * 128 * 2);
  float* WtG = (float*)((char*)xh + (size_t)2 * 3 * 16384 * 128 * 2);

  k_convx<<<4096, 256, 0, stream>>>(x, xh, aff, W, affH, WH);
  k_wt<<<dim3(K0P / 32, N0 / 32, 3), 256, 0, stream>>>(w0, wT0, DDIM, K0P, N0);
  k_wt<<<dim3(N0 / 32, N1 / 32, 3), 256, 0, stream>>>(w1, wT1, N0, N0, N1);
  k_wt<<<dim3(N1 / 32, N2 / 32, 3), 256, 0, stream>>>(w2, wT2, N1, N1, N2);

  const int LDST3 = 3 * 49152;
  hipError_t e1 = hipFuncSetAttribute(reinterpret_cast<const void*>(&k_gemmt3<1>),
                                      hipFuncAttributeMaxDynamicSharedMemorySize, LDST3);
  if (e1 == hipSuccess) {
    // L0: 8x96 = 768 blocks = 3 balanced rounds of 256 CUs.
    k_gemmt3<1><<<dim3(N0 / 128, 96), 512, LDST3, stream>>>(xh, wT0, b0, h0, K0P, N0);
    // L1: 4x96 = 384 blocks = 1.5 rounds (all CUs busy in round 1).
    k_gemmt3<1><<<dim3(N1 / 128, 96), 512, LDST3, stream>>>(h0, wT1, b1, h1, N0, N1);
  } else {
    k_gemm<1><<<dim3(N0 / 128, BBATCH / 128, 3), 256, 0, stream>>>(xh, wT0, b0, h0, nullptr, nullptr, K0P, N0);
    k_gemm<1><<<dim3(N1 / 128, BBATCH / 128, 3), 256, 0, stream>>>(h0, wT1, b1, h1, nullptr, nullptr, N0, N1);
  }
  // L2: k_gemm (768-block grid at 2 blocks/CU; writes z + tH).
  k_gemm<0><<<dim3(N2 / 128, BBATCH / 128, 3), 256, 0, stream>>>(h1, wT2, b2, nullptr, zout, tH, N1, N2);
  k_sg<<<dim3(1, 128, 6), 256, 0, stream>>>(tH, affH, WH, u, WtG);
  k_tail<<<256, 256, 0, stream>>>(zout, tH, u, WtG, Wh, cout);
}

// Round 13
// 287.822 us; speedup vs baseline: 1.0574x; 1.0574x over previous
//
#include <hip/hip_runtime.h>

#define DEVI __device__ __forceinline__

typedef _Float16 f16;
typedef _Float16 f16x8 __attribute__((ext_vector_type(8)));
typedef float f32x4 __attribute__((ext_vector_type(4)));
typedef unsigned int u32;
typedef unsigned long long u64;

#define MM 3
#define BBATCH 8192
#define DDIM 2000
#define ZDIM 256
#define KATT 40
#define K0P 2048
#define N0 1024
#define N1 512
#define N2 256

typedef __attribute__((address_space(1))) u32 gu32;
typedef __attribute__((address_space(3))) u32 lu32;

DEVI void async16(const void* g, void* l) {
  __builtin_amdgcn_global_load_lds((const gu32*)g, (lu32*)l, 16, 0, 0);
}

// ---------------- x -> fp16 (K padded 2000->2048) + small converts (aff, W) ----------------
__global__ void k_convx(const float* __restrict__ x, f16* __restrict__ xh,
                        const float* __restrict__ aff, const float* __restrict__ W,
                        f16* __restrict__ affH, f16* __restrict__ WH) {
  int idx0 = blockIdx.x * 256 + threadIdx.x;
  if (idx0 < 2 * 128 * 128) affH[idx0] = (f16)aff[idx0];
  if (idx0 < 3 * 64 * 128) {
    int m = idx0 >> 13;
    int k = (idx0 >> 7) & 63;
    int f = idx0 & 127;
    WH[idx0] = (k < KATT) ? (f16)W[(m * KATT + k) * 128 + f] : (f16)0.f;
  }
  const long long nch = (long long)MM * BBATCH * (K0P / 8);
  for (long long idx = (long long)blockIdx.x * blockDim.x + threadIdx.x; idx < nch;
       idx += (long long)gridDim.x * blockDim.x) {
    int c8 = (int)(idx & 255);
    long long row = idx >> 8;
    union { f16 h[8]; f16x8 v; } u;
    if (c8 < DDIM / 8) {
      const float* src = x + row * DDIM + c8 * 8;
      float4 a = *reinterpret_cast<const float4*>(src);
      float4 b = *reinterpret_cast<const float4*>(src + 4);
      u.h[0] = (f16)a.x; u.h[1] = (f16)a.y; u.h[2] = (f16)a.z; u.h[3] = (f16)a.w;
      u.h[4] = (f16)b.x; u.h[5] = (f16)b.y; u.h[6] = (f16)b.z; u.h[7] = (f16)b.w;
    } else {
      for (int j = 0; j < 8; ++j) u.h[j] = (f16)0.f;
    }
    *reinterpret_cast<f16x8*>(xh + row * K0P + c8 * 8) = u.v;
  }
}

// ---------------- merged weight transpose+convert for all 3 layers ----------------
// layer0: w0[3][2000][1024] -> wt0[3][1024][2048]; grid chunk 64x32x3 = 6144 blocks
// layer1: w1[3][1024][512]  -> wt1[3][512][1024];  grid chunk 32x16x3 = 1536 blocks
// layer2: w2[3][512][256]   -> wt2[3][256][512];   grid chunk 16x8x3  = 384 blocks
__global__ void k_wtall(const float* __restrict__ w0, f16* __restrict__ wt0,
                        const float* __restrict__ w1, f16* __restrict__ wt1,
                        const float* __restrict__ w2, f16* __restrict__ wt2) {
  __shared__ float tile[32][33];
  const int bid = blockIdx.x;
  const float* w; f16* wt;
  int K, Kpad, N, kx, ny, m;
  if (bid < 6144) {
    w = w0; wt = wt0; K = DDIM; Kpad = K0P; N = N0;
    kx = bid & 63; ny = (bid >> 6) & 31; m = bid >> 11;
  } else if (bid < 7680) {
    int l = bid - 6144;
    w = w1; wt = wt1; K = N0; Kpad = N0; N = N1;
    kx = l & 31; ny = (l >> 5) & 15; m = l >> 9;
  } else {
    int l = bid - 7680;
    w = w2; wt = wt2; K = N1; Kpad = N1; N = N2;
    kx = l & 15; ny = (l >> 4) & 7; m = l >> 7;
  }
  const int k0 = kx * 32, n0 = ny * 32;
  const float* wm = w + (long long)m * K * N;
  f16* wtm = wt + (long long)m * N * Kpad;
  for (int p = 0; p < 4; ++p) {
    int idx = threadIdx.x + p * 256;
    int kk = idx >> 5, nn = idx & 31;
    float v = 0.f;
    if (k0 + kk < K) v = wm[(long long)(k0 + kk) * N + n0 + nn];
    tile[kk][nn] = v;
  }
  __syncthreads();
  for (int p = 0; p < 4; ++p) {
    int idx = threadIdx.x + p * 256;
    int nn = idx >> 5, kk = idx & 31;
    wtm[(long long)(n0 + nn) * Kpad + k0 + kk] = (f16)tile[kk][nn];
  }
}

// ---------------- GEMM (f16 inputs): C[m] = relu(A[m] @ BT[m]^T + bias), 128x128, BK=64 ----------------
template <int OUTF16>
__global__ __launch_bounds__(256, 2) void k_gemm(const f16* __restrict__ A,
                                                 const f16* __restrict__ BT,
                                                 const float* __restrict__ bias,
                                                 f16* __restrict__ outh,
                                                 float* __restrict__ outf,
                                                 f16* __restrict__ tH, int K, int N) {
  __shared__ f16 As[128 * 64];
  __shared__ f16 Bs[128 * 64];
  const int m = blockIdx.z;
  const int gm0 = blockIdx.y * 128;
  const int gn0 = blockIdx.x * 128;
  const int tid = threadIdx.x;
  const int wave = tid >> 6, lane = tid & 63;
  const int wr = wave >> 1, wc = wave & 1;

  const f16* Am = A + (long long)m * BBATCH * K;
  const f16* Bm = BT + (long long)m * N * K;

  const int srow = wave * 32 + (lane >> 3);
  const int sslot = (lane & 7) ^ (lane >> 3);
  const f16* aSrc = Am + (long long)(gm0 + srow) * K + sslot * 8;
  const f16* bSrc = Bm + (long long)(gn0 + srow) * K + sslot * 8;
  char* AsB = (char*)As;
  char* BsB = (char*)Bs;

  f32x4 zero = {0.f, 0.f, 0.f, 0.f};
  f32x4 acc[4][4];
  for (int i = 0; i < 4; ++i)
    for (int j = 0; j < 4; ++j) acc[i][j] = zero;

  for (int kt = 0; kt < K; kt += 64) {
    if (kt) __syncthreads();
#pragma unroll
    for (int q = 0; q < 4; ++q) {
      async16(aSrc + (long long)q * 8 * K + kt, AsB + (wave * 32 + q * 8) * 128);
      async16(bSrc + (long long)q * 8 * K + kt, BsB + (wave * 32 + q * 8) * 128);
    }
    __syncthreads();
#pragma unroll
    for (int ks = 0; ks < 2; ++ks) {
      f16x8 af[4], bf[4];
#pragma unroll
      for (int i = 0; i < 4; ++i) {
        int row = wr * 64 + i * 16 + (lane & 15);
        int slot = (ks * 4 + (lane >> 4)) ^ (row & 7);
        af[i] = *reinterpret_cast<const f16x8*>(AsB + row * 128 + slot * 16);
      }
#pragma unroll
      for (int j = 0; j < 4; ++j) {
        int row = wc * 64 + j * 16 + (lane & 15);
        int slot = (ks * 4 + (lane >> 4)) ^ (row & 7);
        bf[j] = *reinterpret_cast<const f16x8*>(BsB + row * 128 + slot * 16);
      }
#pragma unroll
      for (int i = 0; i < 4; ++i)
#pragma unroll
        for (int j = 0; j < 4; ++j)
          acc[i][j] = __builtin_amdgcn_mfma_f32_16x16x32_f16(af[i], bf[j], acc[i][j], 0, 0, 0);
    }
  }

  const int rowl = (lane >> 4) * 4;
  const int coll = lane & 15;
  for (int j = 0; j < 4; ++j) {
    int col = gn0 + wc * 64 + j * 16 + coll;
    float bv = bias[m * N + col];
    for (int i = 0; i < 4; ++i) {
      int row0 = gm0 + wr * 64 + i * 16 + rowl;
      for (int r = 0; r < 4; ++r) {
        float v = acc[i][j][r] + bv;
        v = v > 0.f ? v : 0.f;
        if constexpr (OUTF16) {
          outh[((long long)m * BBATCH + row0 + r) * N + col] = (f16)v;
        } else {
          outf[((long long)m * BBATCH + row0 + r) * N + col] = v;
          tH[((long long)(m * BBATCH + row0 + r) * 2 + (col & 1)) * 128 + (col >> 1)] = (f16)v;
        }
      }
    }
  }
}

// ---------------- shared macros for the phase-structured GEMMs ----------------
#define LDA_FRAGS(QM)                                                            \
  _Pragma("unroll") for (int ks = 0; ks < 2; ++ks)                               \
  _Pragma("unroll") for (int mf = 0; mf < 4; ++mf) {                             \
    const int row_ = (QM)*128 + wrB + mf * 16 + lrow;                            \
    af[ks][mf] = *reinterpret_cast<const f16x8*>(bufA + row_ * 128 + sl16[ks]);  \
  }

#define LDB_FRAGS(QN)                                                            \
  _Pragma("unroll") for (int ks = 0; ks < 2; ++ks)                               \
  _Pragma("unroll") for (int nf = 0; nf < 2; ++nf) {                             \
    const int row_ = (QN)*128 + wcB + nf * 16 + lrow;                            \
    bf[ks][QN][nf] = *reinterpret_cast<const f16x8*>(bufB + row_ * 128 + sl16[ks]); \
  }

#define DO_MFMA(QI, QN)                                                          \
  __builtin_amdgcn_s_setprio(1);                                                 \
  _Pragma("unroll") for (int ks = 0; ks < 2; ++ks)                               \
  _Pragma("unroll") for (int mf = 0; mf < 4; ++mf)                               \
  _Pragma("unroll") for (int nf = 0; nf < 2; ++nf)                               \
    acc[QI][mf * 2 + nf] = __builtin_amdgcn_mfma_f32_16x16x32_f16(                \
        af[ks][mf], bf[ks][QN][nf], acc[QI][mf * 2 + nf], 0, 0, 0);              \
  __builtin_amdgcn_s_setprio(0);

#define SYNCV(VMN)                                         \
  asm volatile("s_waitcnt vmcnt(" #VMN ")" ::: "memory");  \
  __builtin_amdgcn_s_barrier();

#define LGKM0                                              \
  asm volatile("s_waitcnt lgkmcnt(0)" ::: "memory");       \
  __builtin_amdgcn_sched_barrier(0);

#define ENDBAR __builtin_amdgcn_s_barrier();

// ---------------- 8-phase 256x256 GEMM (round-5 proven schedule) ----------------
template <int OUTF16>
__global__ __launch_bounds__(512, 2) void k_gemm8(const f16* __restrict__ A,
                                                  const f16* __restrict__ BT,
                                                  const float* __restrict__ bias,
                                                  f16* __restrict__ outh,
                                                  float* __restrict__ outf,
                                                  f16* __restrict__ tH, int K, int N) {
  extern __shared__ char lds[];  // 2 * 65536
  const int lin = blockIdx.y * gridDim.x + blockIdx.x;
  const int cpx = (gridDim.x * gridDim.y) >> 3;
  const int swz = (lin & 7) * cpx + (lin >> 3);
  const int bx = swz % gridDim.x;
  const int byy = swz / gridDim.x;  // 0..95
  const int m = byy >> 5;
  const int gm0 = (byy & 31) * 256;
  const int gn0 = bx * 256;

  const int tid = threadIdx.x;
  const int wave = tid >> 6, lane = tid & 63;
  const int wrB = (wave >> 2) * 64;
  const int wcB = (wave & 3) * 32;
  const int lrow = lane & 15;
  int sl16[2];
#pragma unroll
  for (int ks = 0; ks < 2; ++ks) sl16[ks] = (((ks * 4) + (lane >> 4)) ^ (lane & 7)) * 16;

  const f16* Am = A + (long long)m * BBATCH * K;
  const f16* Bm = BT + (long long)m * N * K;
  const int srow = tid >> 3;
  const int slog = (tid & 7) ^ (srow & 7);

  auto stage = [&](int t, int hsel) {
    const int isB = (hsel == 1 || hsel == 2) ? 1 : 0;
    const int h = (hsel == 2 || hsel == 3) ? 1 : 0;
    const long long grow = (long long)(isB ? gn0 : gm0) + h * 128 + srow;
    const f16* src = (isB ? Bm : Am) + grow * K + ((long long)t << 6) + slog * 8;
    char* dst = lds + ((t & 1) << 16) + isB * 32768 + h * 16384 + srow * 128 + (tid & 7) * 16;
    async16(src, dst);
    async16(src + (long long)64 * K, dst + 8192);
  };

  f16x8 af[2][4];
  f16x8 bf[2][2][2];
  f32x4 acc[4][8];
  f32x4 zero = {0.f, 0.f, 0.f, 0.f};
#pragma unroll
  for (int qi = 0; qi < 4; ++qi)
#pragma unroll
    for (int f = 0; f < 8; ++f) acc[qi][f] = zero;

  const int NT = K >> 6;
  stage(0, 0); stage(0, 1); stage(0, 2); stage(0, 3);

  for (int t = 0; t < NT - 1; ++t) {
    const char* bufA = lds + ((t & 1) << 16);
    const char* bufB = bufA + 32768;
    stage(t + 1, 0);
    SYNCV(6)
    LDA_FRAGS(0) LDB_FRAGS(0) LGKM0
    DO_MFMA(0, 0) ENDBAR
    stage(t + 1, 1);
    SYNCV(6)
    LDB_FRAGS(1) LGKM0
    DO_MFMA(1, 1) ENDBAR
    stage(t + 1, 2);
    SYNCV(6)
    LDA_FRAGS(1) LGKM0
    DO_MFMA(2, 1) ENDBAR
    stage(t + 1, 3);
    DO_MFMA(3, 0)
  }
  {
    const int t = NT - 1;
    const char* bufA = lds + ((t & 1) << 16);
    const char* bufB = bufA + 32768;
    SYNCV(4)
    LDA_FRAGS(0) LDB_FRAGS(0) LGKM0
    DO_MFMA(0, 0) ENDBAR
    SYNCV(2)
    LDB_FRAGS(1) LGKM0
    DO_MFMA(1, 1) ENDBAR
    SYNCV(0)
    LDA_FRAGS(1) LGKM0
    DO_MFMA(2, 1) ENDBAR
    DO_MFMA(3, 0)
  }

  const int rowl = (lane >> 4) * 4;
  const int coll = lane & 15;
#pragma unroll
  for (int qi = 0; qi < 4; ++qi) {
    const int qm = (qi >= 2) ? 1 : 0;
    const int qn = (qi == 1 || qi == 2) ? 1 : 0;
#pragma unroll
    for (int nf = 0; nf < 2; ++nf) {
      int col = gn0 + qn * 128 + wcB + nf * 16 + coll;
      float bv = bias[m * N + col];
#pragma unroll
      for (int mf = 0; mf < 4; ++mf) {
        int row0 = gm0 + qm * 128 + wrB + mf * 16 + rowl;
#pragma unroll
        for (int r = 0; r < 4; ++r) {
          float v = acc[qi][mf * 2 + nf][r] + bv;
          v = v > 0.f ? v : 0.f;
          if constexpr (OUTF16) {
            outh[((long long)m * BBATCH + row0 + r) * N + col] = (f16)v;
          } else {
            outf[((long long)m * BBATCH + row0 + r) * N + col] = v;
            tH[((long long)(m * BBATCH + row0 + r) * 2 + (col & 1)) * 128 + (col >> 1)] = (f16)v;
          }
        }
      }
    }
  }
}

// ---------------- half-height variant: BM=128 x BN=256, balanced 768-block grid ----------------
template <int OUTF16>
__global__ __launch_bounds__(512, 2) void k_gemm2h(const f16* __restrict__ A,
                                                   const f16* __restrict__ BT,
                                                   const float* __restrict__ bias,
                                                   f16* __restrict__ outh, int K, int N) {
  extern __shared__ char lds[];  // 2 * 49152
  const int lin = blockIdx.y * gridDim.x + blockIdx.x;
  const int cpx = (gridDim.x * gridDim.y) >> 3;
  const int swz = (lin & 7) * cpx + (lin >> 3);
  const int bx = swz % gridDim.x;
  const int byy = swz / gridDim.x;  // 0..191
  const int m = byy >> 6;
  const int gm0 = (byy & 63) * 128;
  const int gn0 = bx * 256;

  const int tid = threadIdx.x;
  const int wave = tid >> 6, lane = tid & 63;
  const int wrB = (wave >> 2) * 64;  // 0/64 within the 128 rows
  const int wcB = (wave & 3) * 32;   // within a 128-col quadrant
  const int lrow = lane & 15;
  int sl16[2];
#pragma unroll
  for (int ks = 0; ks < 2; ++ks) sl16[ks] = (((ks * 4) + (lane >> 4)) ^ (lane & 7)) * 16;

  const f16* Am = A + (long long)m * BBATCH * K;
  const f16* Bm = BT + (long long)m * N * K;
  const int srow = tid >> 3;
  const int slog = (tid & 7) ^ (srow & 7);

  auto stage = [&](int t, int hsel) {  // 0 = B half0, 1 = A, 2 = B half1
    const int isB = (hsel != 1) ? 1 : 0;
    const int h = (hsel == 2) ? 1 : 0;
    const long long grow = isB ? ((long long)gn0 + h * 128 + srow) : ((long long)gm0 + srow);
    const f16* src = (isB ? Bm : Am) + grow * K + ((long long)t << 6) + slog * 8;
    char* dst = lds + (t & 1) * 49152 + (isB ? 16384 + h * 16384 : 0) + srow * 128 + (tid & 7) * 16;
    async16(src, dst);
    async16(src + (long long)64 * K, dst + 8192);
  };

  f16x8 af[2][4];
  f16x8 bf[2][2][2];
  f32x4 acc[2][8];
  f32x4 zero = {0.f, 0.f, 0.f, 0.f};
#pragma unroll
  for (int qi = 0; qi < 2; ++qi)
#pragma unroll
    for (int f = 0; f < 8; ++f) acc[qi][f] = zero;

  const int NT = K >> 6;
  stage(0, 0); stage(0, 1); stage(0, 2);  // B0, A, B1 (order matters for the vmcnt ledger)

  for (int t = 0; t < NT - 1; ++t) {
    const char* bufA = lds + (t & 1) * 49152;
    const char* bufB = bufA + 16384;
    stage(t + 1, 0); stage(t + 1, 1);
    SYNCV(6)
    LDA_FRAGS(0) LDB_FRAGS(0) LGKM0
    DO_MFMA(0, 0) ENDBAR
    stage(t + 1, 2);
    SYNCV(6)
    LDB_FRAGS(1) LGKM0
    DO_MFMA(1, 1) ENDBAR
  }
  {
    const int t = NT - 1;
    const char* bufA = lds + (t & 1) * 49152;
    const char* bufB = bufA + 16384;
    SYNCV(2)
    LDA_FRAGS(0) LDB_FRAGS(0) LGKM0
    DO_MFMA(0, 0) ENDBAR
    SYNCV(0)
    LDB_FRAGS(1) LGKM0
    DO_MFMA(1, 1)
  }

  const int rowl = (lane >> 4) * 4;
  const int coll = lane & 15;
#pragma unroll
  for (int qi = 0; qi < 2; ++qi) {
#pragma unroll
    for (int nf = 0; nf < 2; ++nf) {
      int col = gn0 + qi * 128 + wcB + nf * 16 + coll;
      float bv = bias[m * N + col];
#pragma unroll
      for (int mf = 0; mf < 4; ++mf) {
        int row0 = gm0 + wrB + mf * 16 + rowl;
#pragma unroll
        for (int r = 0; r < 4; ++r) {
          float v = acc[qi][mf * 2 + nf][r] + bv;
          v = v > 0.f ? v : 0.f;
          outh[((long long)m * BBATCH + row0 + r) * N + col] = (f16)v;
        }
      }
    }
  }
}

// ---------------- small GEMMs for the attention tail ----------------
__global__ __launch_bounds__(256, 2) void k_sg(const f16* __restrict__ tH,
                                               const f16* __restrict__ affH,
                                               const f16* __restrict__ WH,
                                               f16* __restrict__ u, float* __restrict__ WtG) {
  __shared__ f16 As[128 * 128];
  __shared__ f16 Bs[128 * 128];
  const int zb = blockIdx.z;
  const int gm0 = blockIdx.y * 128;
  const bool isU = (zb < 3);
  const int p = isU ? zb : zb - 3;
  const int src = isU ? ((p == 0) ? 1 : 2) : p;
  const f16* Am = tH + (long long)src * 16384 * 128;
  const f16* Bm;
  int brows;
  if (isU) {
    int km = (p == 1) ? 1 : 0;
    Bm = affH + km * 128 * 128;
    brows = 128;
  } else {
    Bm = WH + p * 64 * 128;
    brows = 64;
  }

  const int tid = threadIdx.x;
  const int wave = tid >> 6, lane = tid & 63;
  const int wr = wave >> 1, wc = wave & 1;
  char* AsB = (char*)As;
  char* BsB = (char*)Bs;

#pragma unroll
  for (int q = 0; q < 8; ++q) {
    int sb = q * 4 + wave;
    int row = sb * 4 + (lane >> 4);
    int lsl = (lane & 15) ^ (row & 7);
    async16(Am + (long long)(gm0 + row) * 128 + lsl * 8, AsB + sb * 1024);
    if (sb * 4 < brows)
      async16(Bm + (long long)row * 128 + lsl * 8, BsB + sb * 1024);
  }
  if (brows == 64) {
    f16x8 z8 = {};
    for (int idx = tid; idx < 1024; idx += 256) {
      int row = 64 + (idx >> 4), sl = idx & 15;
      *reinterpret_cast<f16x8*>(BsB + row * 256 + sl * 16) = z8;
    }
  }
  __syncthreads();

  f32x4 zero = {0.f, 0.f, 0.f, 0.f};
  f32x4 acc[4][4];
  for (int i = 0; i < 4; ++i)
    for (int j = 0; j < 4; ++j) acc[i][j] = zero;

#pragma unroll
  for (int ks = 0; ks < 4; ++ks) {
    f16x8 af[4], bf[4];
#pragma unroll
    for (int i = 0; i < 4; ++i) {
      int row = wr * 64 + i * 16 + (lane & 15);
      int slot = (ks * 4 + (lane >> 4)) ^ (row & 7);
      af[i] = *reinterpret_cast<const f16x8*>(AsB + row * 256 + slot * 16);
    }
#pragma unroll
    for (int j = 0; j < 4; ++j) {
      int row = wc * 64 + j * 16 + (lane & 15);
      int slot = (ks * 4 + (lane >> 4)) ^ (row & 7);
      bf[j] = *reinterpret_cast<const f16x8*>(BsB + row * 256 + slot * 16);
    }
#pragma unroll
    for (int i = 0; i < 4; ++i)
#pragma unroll
      for (int j = 0; j < 4; ++j)
        acc[i][j] = __builtin_amdgcn_mfma_f32_16x16x32_f16(af[i], bf[j], acc[i][j], 0, 0, 0);
  }

  const int rowl = (lane >> 4) * 4;
  const int coll = lane & 15;
  if (isU) {
    for (int j = 0; j < 4; ++j) {
      int col = wc * 64 + j * 16 + coll;
      for (int i = 0; i < 4; ++i) {
        int row0 = gm0 + wr * 64 + i * 16 + rowl;
        for (int r = 0; r < 4; ++r)
          u[((long long)p * 16384 + row0 + r) * 128 + col] = (f16)acc[i][j][r];
      }
    }
  } else if (wc == 0) {
    for (int j = 0; j < 4; ++j) {
      int col = j * 16 + coll;
      for (int i = 0; i < 4; ++i) {
        int row0 = gm0 + wr * 64 + i * 16 + rowl;
        for (int r = 0; r < 4; ++r)
          WtG[((long long)p * 16384 + row0 + r) * 64 + col] = acc[i][j][r];
      }
    }
  }
}

// ---------------- fused tail: afm dots + tanh/softmax + coalesced output ----------------
DEVI float dot128(const f16* __restrict__ a, const f16* __restrict__ b) {
  float s = 0.f;
#pragma unroll
  for (int ch = 0; ch < 16; ++ch) {
    f16x8 av = *reinterpret_cast<const f16x8*>(a + ch * 8);
    f16x8 bv = *reinterpret_cast<const f16x8*>(b + ch * 8);
#pragma unroll
    for (int q = 0; q < 8; ++q) s += (float)av[q] * (float)bv[q];
  }
  return s;
}

DEVI float ftanh(float x) {
  x = fminf(fmaxf(x, -15.f), 15.f);
  float t = __expf(-2.f * x);
  return (1.f - t) / (1.f + t);
}

#define BB 32
__global__ void k_tail(const float* __restrict__ z, const f16* __restrict__ tH,
                       const f16* __restrict__ u, const float* __restrict__ WtG,
                       const float* __restrict__ Wh, float* __restrict__ out) {
  __shared__ float aa[BB][6][2];
  const int tid = threadIdx.x;
  const int bbase = blockIdx.x * BB;

  if (tid < BB * 6) {
    int bb = tid / 6, q = tid % 6;
    int b = bbase + bb;
    int i = q >> 1;
    int j = (q & 1) ? ((i == 2) ? 1 : 2) : ((i == 0) ? 1 : 0);
    int a = i < j ? i : j;
    int b2 = i < j ? j : i;
    int pidx = a + b2 - 1;
    bool trans = (i > j);

    float afm[2][2];
#pragma unroll
    for (int c = 0; c < 2; ++c)
#pragma unroll
      for (int d = 0; d < 2; ++d)
        afm[c][d] = dot128(tH + ((long long)(a * BBATCH + b) * 2 + c) * 128,
                           u + ((long long)pidx * 16384 + b * 2 + d) * 128);

    float m00, m01, m10, m11;
    if (!trans) { m00 = afm[0][0]; m01 = afm[0][1]; m10 = afm[1][0]; m11 = afm[1][1]; }
    else        { m00 = afm[0][0]; m01 = afm[1][0]; m10 = afm[0][1]; m11 = afm[1][1]; }

    const float* wb0 = WtG + ((long long)b2 * 16384 + b * 2 + 0) * 64;
    const float* wb1 = WtG + ((long long)b2 * 16384 + b * 2 + 1) * 64;
    const float* wa0 = WtG + ((long long)a * 16384 + b * 2 + 0) * 64;
    const float* wa1 = WtG + ((long long)a * 16384 + b * 2 + 1) * 64;
    const float* wh = Wh + (i * 3 + j) * KATT;
    float s0 = 0.f, s1 = 0.f;
    for (int k = 0; k < KATT; ++k) {
      float a0v = wa0[k], a1v = wa1[k];
      float h0 = ftanh(wb0[k] + a0v * m00 + a1v * m10);
      float h1 = ftanh(wb1[k] + a0v * m01 + a1v * m11);
      float w = wh[k];
      s0 += w * h0;
      s1 += w * h1;
    }
    float mx = fmaxf(s0, s1);
    float e0 = __expf(s0 - mx), e1 = __expf(s1 - mx);
    float inv = 1.f / (e0 + e1);
    aa[bb][q][0] = e0 * inv;
    aa[bb][q][1] = e1 * inv;
  }
  __syncthreads();

  for (int idx = tid; idx < BB * 6 * 256; idx += 256) {
    int zz = idx & 255;
    int r = idx >> 8;
    int q = r % 6;
    int bb = r / 6;
    int iM = q >> 1;
    float av = aa[bb][q][zz & 1];
    float tv = z[((long long)iM * BBATCH + bbase + bb) * ZDIM + zz];
    out[(long long)(bbase + bb) * 1536 + q * 256 + zz] = av * tv;
  }
}

extern "C" void kernel_launch(void* const* d_in, const int* in_sizes, int n_in, void* d_out,
                              int out_size, void* d_ws, size_t ws_size, hipStream_t stream) {
  const float* x = (const float*)d_in[0];
  const float* w0 = (const float*)d_in[1];
  const float* b0 = (const float*)d_in[2];
  const float* w1 = (const float*)d_in[3];
  const float* b1 = (const float*)d_in[4];
  const float* w2 = (const float*)d_in[5];
  const float* b2 = (const float*)d_in[6];
  const float* aff = (const float*)d_in[7];
  const float* W = (const float*)d_in[8];
  const float* Wh = (const float*)d_in[9];
  float* zout = (float*)d_out;
  float* cout = zout + (long long)MM * BBATCH * ZDIM;

  char* ws = (char*)d_ws;
  size_t off = 0;
  auto alloc = [&](size_t bytes) {
    char* p = ws + off;
    off += (bytes + 255) & ~(size_t)255;
    return p;
  };
  f16* xh = (f16*)alloc((size_t)MM * BBATCH * K0P * 2);
  f16* wT0 = (f16*)alloc((size_t)MM * N0 * K0P * 2);
  f16* wT1 = (f16*)alloc((size_t)MM * N1 * N0 * 2);
  f16* wT2 = (f16*)alloc((size_t)MM * N2 * N1 * 2);
  f16* h0 = (f16*)alloc((size_t)MM * BBATCH * N0 * 2);
  f16* h1 = (f16*)alloc((size_t)MM * BBATCH * N1 * 2);
  f16* affH = (f16*)alloc((size_t)2 * 128 * 128 * 2);
  f16* WH = (f16*)alloc((size_t)3 * 64 * 128 * 2);
  if (ws_size < off) return;

  // tail buffers alias xh (dead after L0 GEMM)
  f16* tH = (f16*)xh;
  f16* u = (f16*)((char*)xh + (size_t)3 * 16384 * 128 * 2);
  float* WtG = (float*)((char*)xh + (size_t)2 * 3 * 16384 * 128 * 2);

  k_convx<<<4096, 256, 0, stream>>>(x, xh, aff, W, affH, WH);
  k_wtall<<<8064, 256, 0, stream>>>(w0, wT0, w1, wT1, w2, wT2);

  const int LDS8 = 2 * 65536;
  const int LDS2H = 2 * 49152;
  hipError_t e1 = hipFuncSetAttribute(reinterpret_cast<const void*>(&k_gemm8<1>),
                                      hipFuncAttributeMaxDynamicSharedMemorySize, LDS8);
  hipError_t e2 = hipFuncSetAttribute(reinterpret_cast<const void*>(&k_gemm2h<1>),
                                      hipFuncAttributeMaxDynamicSharedMemorySize, LDS2H);
  if (e1 == hipSuccess && e2 == hipSuccess) {
    // L0: half-height tile -> 4*192 = 768 blocks = exactly 3 rounds of 256 CUs (balanced).
    k_gemm2h<1><<<dim3(N0 / 256, 192), 512, LDS2H, stream>>>(xh, wT0, b0, h0, K0P, N0);
    // L1: 2*96 = 192 blocks = 1 round (balanced already).
    k_gemm8<1><<<dim3(N1 / 256, 96), 512, LDS8, stream>>>(h0, wT1, b1, h1, nullptr, nullptr, N0, N1);
  } else {
    k_gemm<1><<<dim3(N0 / 128, BBATCH / 128, 3), 256, 0, stream>>>(xh, wT0, b0, h0, nullptr, nullptr, K0P, N0);
    k_gemm<1><<<dim3(N1 / 128, BBATCH / 128, 3), 256, 0, stream>>>(h0, wT1, b1, h1, nullptr, nullptr, N0, N1);
  }
  // L2: k_gemm (768-block grid at 2 blocks/CU; writes z + tH).
  k_gemm<0><<<dim3(N2 / 128, BBATCH / 128, 3), 256, 0, stream>>>(h1, wT2, b2, nullptr, zout, tH, N1, N2);
  k_sg<<<dim3(1, 128, 6), 256, 0, stream>>>(tH, affH, WH, u, WtG);
  k_tail<<<256, 256, 0, stream>>>(zout, tH, u, WtG, Wh, cout);
}